// Round 3
// baseline (2689.829 us; speedup 1.0000x reference)
//
#include <hip/hip_runtime.h>
#include <stdint.h>
#include <stddef.h>

#define N_AG 81

typedef __bf16 bf16x8 __attribute__((ext_vector_type(8)));
typedef float f32x4 __attribute__((ext_vector_type(4)));
typedef f32x4 __attribute__((aligned(4))) f32x4u;
typedef uint32_t u32v4 __attribute__((ext_vector_type(4)));
typedef uint32_t u32v2 __attribute__((ext_vector_type(2)));

// s_par layout (float idx): [0,128) bias, [128,256) ln_gamma, [256,384) ln_beta
#define PB 0
#define PG 128
#define PBT 256

__device__ __forceinline__ unsigned short b2u(__bf16 h) {
  return __builtin_bit_cast(unsigned short, h);
}

__device__ __forceinline__ f32x4 f4z() { f32x4 v; v[0]=0.f; v[1]=0.f; v[2]=0.f; v[3]=0.f; return v; }

__device__ __forceinline__ bf16x8 ld_frag(const uint8_t* p) {
  u32v4 v = *(const u32v4*)p;
  return __builtin_bit_cast(bf16x8, v);
}

__device__ __forceinline__ f32x4 mfma16(bf16x8 a, bf16x8 b, f32x4 c) {
  return __builtin_amdgcn_mfma_f32_16x16x32_bf16(a, b, c, 0, 0, 0);
}

// butterfly sum over the 16 lanes of a DPP row (our q-dimension); all lanes get the sum.
__device__ __forceinline__ float wave16_sum(float v) {
  v += __builtin_bit_cast(float, __builtin_amdgcn_update_dpp(0, __builtin_bit_cast(int, v), 0xB1, 0xF, 0xF, true));  // quad xor1
  v += __builtin_bit_cast(float, __builtin_amdgcn_update_dpp(0, __builtin_bit_cast(int, v), 0x4E, 0xF, 0xF, true));  // quad xor2
  v += __builtin_bit_cast(float, __builtin_amdgcn_update_dpp(0, __builtin_bit_cast(int, v), 0x141, 0xF, 0xF, true)); // half mirror
  v += __builtin_bit_cast(float, __builtin_amdgcn_update_dpp(0, __builtin_bit_cast(int, v), 0x140, 0xF, 0xF, true)); // mirror
  return v;
}

__device__ __forceinline__ bf16x8 mk_frag(const unsigned short (&us)[8]) {
  u32v4 pk;
  pk[0] = (uint32_t)us[0] | ((uint32_t)us[1] << 16);
  pk[1] = (uint32_t)us[2] | ((uint32_t)us[3] << 16);
  pk[2] = (uint32_t)us[4] | ((uint32_t)us[5] << 16);
  pk[3] = (uint32_t)us[6] | ((uint32_t)us[7] << 16);
  return __builtin_bit_cast(bf16x8, pk);
}

// BN+ReLU applied to 8 bf16 y-values (two 8B words) with packed (scale,shift) coefs.
__device__ __forceinline__ bf16x8 bn_frag(u32v2 lo, u32v2 hi, const f32x4 (&cf)[4]) {
  bf16x8 r;
  #pragma unroll
  for (int j = 0; j < 8; ++j) {
    uint32_t wrd = (j < 4) ? lo[(j >> 1) & 1] : hi[(j >> 1) & 1];
    uint32_t us = (j & 1) ? (wrd >> 16) : (wrd & 0xffffu);
    float f = __builtin_bit_cast(float, us << 16);
    float h = fmaf(f, cf[j >> 1][(j & 1) * 2], cf[j >> 1][(j & 1) * 2 + 1]);
    r[j] = (__bf16)fmaxf(h, 0.f);
  }
  return r;
}

// fused bias + layernorm (single-pass sums, var = E[x^2] - mu^2)
__device__ __forceinline__ void bias_ln(f32x4 (&acc)[8][2], const float* s_par, int g) {
  #pragma unroll
  for (int nf = 0; nf < 2; ++nf) {
    float s = 0.f, qs = 0.f;
    #pragma unroll
    for (int mf = 0; mf < 8; ++mf) {
      #pragma unroll
      for (int rg = 0; rg < 4; ++rg) {
        float tv = acc[mf][nf][rg] + s_par[PB + 16 * mf + 4 * g + rg];
        acc[mf][nf][rg] = tv;
        s += tv;
        qs = fmaf(tv, tv, qs);
      }
    }
    s += __shfl_xor(s, 16);  s += __shfl_xor(s, 32);
    qs += __shfl_xor(qs, 16); qs += __shfl_xor(qs, 32);
    float mu = s * (1.f / 128.f);
    float var = qs * (1.f / 128.f) - mu * mu;
    float rstd = rsqrtf(var + 1e-12f);
    #pragma unroll
    for (int mf = 0; mf < 8; ++mf) {
      #pragma unroll
      for (int rg = 0; rg < 4; ++rg) {
        int o = 16 * mf + 4 * g + rg;
        acc[mf][nf][rg] = (acc[mf][nf][rg] - mu) * rstd * s_par[PG + o] + s_par[PBT + o];
      }
    }
  }
}

// per-wave BN-stat partial -> global atomics (butterfly over q lanes first)
__device__ __forceinline__ void stats_atomic(const f32x4 (&acc)[8][2], float* pS, float* pQ,
                                             int g, int q) {
  #pragma unroll
  for (int mf = 0; mf < 8; ++mf) {
    #pragma unroll
    for (int rg = 0; rg < 4; ++rg) {
      float a0v = acc[mf][0][rg], a1v = acc[mf][1][rg];
      float s = a0v + a1v;
      float qq = fmaf(a0v, a0v, a1v * a1v);
      s = wave16_sum(s);
      qq = wave16_sum(qq);
      if (q == 0) {
        int o = 16 * mf + 4 * g + rg;
        atomicAdd(pS + o, s);
        atomicAdd(pQ + o, qq);
      }
    }
  }
}

// store accumulator tile to the y-image in MFMA-acc layout:
// chunk (mf,nf) of 2048B, offset t*8 holds y[o=16mf+4g+{0..3}][b=32wv+16nf+q] as 4 bf16.
__device__ __forceinline__ void store_ytile(const f32x4 (&acc)[8][2], uint8_t* ytile, int t) {
  #pragma unroll
  for (int mf = 0; mf < 8; ++mf) {
    #pragma unroll
    for (int nf = 0; nf < 2; ++nf) {
      u32v2 pk;
      pk[0] = (uint32_t)b2u((__bf16)acc[mf][nf][0]) | ((uint32_t)b2u((__bf16)acc[mf][nf][1]) << 16);
      pk[1] = (uint32_t)b2u((__bf16)acc[mf][nf][2]) | ((uint32_t)b2u((__bf16)acc[mf][nf][3]) << 16);
      *(u32v2*)(ytile + ((((uint32_t)mf << 1) + nf) << 11) + t * 8) = pk;
    }
  }
}

// ---------- prep kernels ----------
// w1img: [o=128][k=64] bf16 swizzled, k-order: 0..47 glob (W1 rows 10..57), 48..57 zones, pad.
// w2img: [o=128][k=128] bf16 swizzled. woimg: [d=16][k=128] bf16 swizzled (rows 5..15 zero).
__global__ void prep_weights(const float* __restrict__ W1, const float* __restrict__ W2,
                             const float* __restrict__ Wout,
                             uint8_t* __restrict__ w1img, uint8_t* __restrict__ w2img,
                             uint8_t* __restrict__ woimg) {
  const int a = blockIdx.x, t = threadIdx.x;
  for (int i = t; i < 128 * 64; i += 256) {
    int o = i & 127, kk = i >> 7;
    float v;
    if (kk < 48)      v = W1[((size_t)a * 58 + (10 + kk)) * 128 + o];
    else if (kk < 58) v = W1[((size_t)a * 58 + (kk - 48)) * 128 + o];
    else              v = 0.f;
    uint32_t cb = 2u * kk;
    uint32_t phys = o * 128 + (((cb & ~15u) ^ (((uint32_t)o & 7u) << 4)) | (cb & 15u));
    *(unsigned short*)(w1img + (size_t)a * 16384 + phys) = b2u((__bf16)v);
  }
  for (int i = t; i < 128 * 128; i += 256) {
    int o = i & 127, kk = i >> 7;
    float v = W2[((size_t)a * 128 + kk) * 128 + o];
    uint32_t cb = 2u * kk;
    uint32_t phys = o * 256 + (((cb & ~15u) ^ (((uint32_t)o & 7u) << 4)) | (cb & 15u));
    *(unsigned short*)(w2img + (size_t)a * 32768 + phys) = b2u((__bf16)v);
  }
  for (int i = t; i < 16 * 128; i += 256) {
    int k = i & 127, d = i >> 7;
    float v = (d < 5) ? Wout[((size_t)a * 128 + k) * 5 + d] : 0.f;
    uint32_t cb = 2u * k;
    uint32_t phys = d * 256 + (((cb & ~15u) ^ (((uint32_t)d & 7u) << 4)) | (cb & 15u));
    *(unsigned short*)(woimg + (size_t)a * 4096 + phys) = b2u((__bf16)v);
  }
}

// packed bf16 image of obs[:, :48], 96B per row.
__global__ void prep_obs(const float* __restrict__ obs, uint8_t* __restrict__ globimg) {
  const int row = blockIdx.x * 256 + threadIdx.x;
  if (row >= 16384) return;
  const float* orow = obs + (size_t)row * 210;
  uint8_t* dst = globimg + (size_t)row * 96;
  #pragma unroll
  for (int c = 0; c < 6; ++c) {
    u32v4 pk;
    #pragma unroll
    for (int e = 0; e < 4; ++e) {
      pk[e] = (uint32_t)b2u((__bf16)orow[8 * c + 2 * e]) |
              ((uint32_t)b2u((__bf16)orow[8 * c + 2 * e + 1]) << 16);
    }
    *(u32v4*)(dst + 16 * c) = pk;
  }
}

// finalize BN coefs from atomic sums: bn = {rs, beta - mu*rs}
__global__ void reduce_bn(const float* __restrict__ S, const float* __restrict__ Q,
                          const float* __restrict__ beta, float2* __restrict__ bn, int a0) {
  const int a = a0 + blockIdx.x, k = threadIdx.x;
  float mu = S[a * 128 + k] * (1.f / 16384.f);
  float var = Q[a * 128 + k] * (1.f / 16384.f) - mu * mu;
  float rs = rsqrtf(var + 1e-3f);  // BN_EPS
  bn[a * 128 + k] = make_float2(rs, beta[a * 128 + k] - mu * rs);
}

// ---------- pass 1: GEMM1 + LN1 -> y1 (acc-layout bf16) + BN1 stats ----------
__launch_bounds__(256, 4)
__global__ void pass1_kernel(const float* __restrict__ obs, const int* __restrict__ nidx,
                             const float* __restrict__ b1, const float* __restrict__ ln1g,
                             const float* __restrict__ ln1b,
                             const uint8_t* __restrict__ w1img,
                             const uint8_t* __restrict__ globimg,
                             float* __restrict__ statS, float* __restrict__ statQ,
                             uint8_t* __restrict__ yimg, int a0) {
  __shared__ __align__(16) uint8_t s_w1[16384];
  __shared__ float s_par[384];

  const int t = threadIdx.x;
  const int wv = t >> 6, l = t & 63, g = l >> 4, q = l & 15;
  const int a = a0 + (blockIdx.x >> 5);
  const int sub = blockIdx.x & 31;

  const int r9 = a / 9, c9 = a - 9 * r9;
  const int deg = 1 + (r9 > 0) + (r9 < 8) + (c9 > 0) + (c9 < 8);
  int nid[5];
  #pragma unroll
  for (int d = 0; d < 5; ++d) nid[d] = __builtin_amdgcn_readfirstlane(nidx[a * 5 + d]);

  const uint8_t* w1src = w1img + (size_t)a * 16384;
  #pragma unroll
  for (int i = 0; i < 4; ++i) ((u32v4*)s_w1)[t + 256 * i] = ((const u32v4*)w1src)[t + 256 * i];
  if (t < 128) {
    s_par[PB + t] = b1[a * 128 + t];
    s_par[PG + t] = ln1g[a * 128 + t];
    s_par[PBT + t] = ln1b[a * 128 + t];
  }
  __syncthreads();

  float* pS = statS + a * 128;
  float* pQ = statQ + a * 128;

  for (int tt = 0; tt < 4; ++tt) {
    const int tile = sub * 4 + tt;

    // B-fragments straight from globimg / gathered zones (no LDS staging)
    bf16x8 bfr[2][2];
    #pragma unroll
    for (int ks = 0; ks < 2; ++ks) {
      #pragma unroll
      for (int nf = 0; nf < 2; ++nf) {
        const int brow = tile * 128 + 32 * wv + 16 * nf + q;
        if (ks == 1 && g >= 2) {
          const float* orow = obs + (size_t)brow * 210;
          unsigned short us[8];
          if (g == 2) {
            #pragma unroll
            for (int e = 0; e < 8; ++e) {
              float v;
              if (e < 5) v = (e < deg) ? orow[48 + nid[e]] : 0.f;
              else       v = ((e - 5) < deg) ? orow[129 + nid[e - 5]] : 0.f;
              us[e] = b2u((__bf16)v);
            }
          } else {
            #pragma unroll
            for (int e = 0; e < 8; ++e) {
              float v = (e < 2 && (3 + e) < deg) ? orow[129 + nid[3 + e]] : 0.f;
              us[e] = b2u((__bf16)v);
            }
          }
          bfr[ks][nf] = mk_frag(us);
        } else {
          bfr[ks][nf] = *(const bf16x8*)(globimg + (size_t)brow * 96 + (32 * ks + 8 * g) * 2);
        }
      }
    }

    f32x4 acc[8][2];
    #pragma unroll
    for (int mf = 0; mf < 8; ++mf) { acc[mf][0] = f4z(); acc[mf][1] = f4z(); }
    #pragma unroll
    for (int ks = 0; ks < 2; ++ks) {
      #pragma unroll
      for (int mf = 0; mf < 8; ++mf) {
        uint32_t r = 16 * mf + q;
        uint32_t cb = ((uint32_t)(64 * ks + 16 * g)) ^ ((r & 7u) << 4);
        bf16x8 af = ld_frag(s_w1 + r * 128 + cb);
        acc[mf][0] = mfma16(af, bfr[ks][0], acc[mf][0]);
        acc[mf][1] = mfma16(af, bfr[ks][1], acc[mf][1]);
      }
    }

    bias_ln(acc, s_par, g);
    stats_atomic(acc, pS, pQ, g, q);

    uint8_t* ytile = yimg + ((((size_t)(a - a0)) * 128 + tile) << 15);
    store_ytile(acc, ytile, t);
  }
}

// ---------- pass 2: h1=BN1+ReLU(y1) on the fly, GEMM2 + LN2 -> y2 (in place) + BN2 stats ----
__launch_bounds__(256, 4)
__global__ void pass2_kernel(const float* __restrict__ b2, const float* __restrict__ ln2g,
                             const float* __restrict__ ln2b,
                             const uint8_t* __restrict__ w2img,
                             const float2* __restrict__ bn1,
                             float* __restrict__ statS, float* __restrict__ statQ,
                             uint8_t* __restrict__ yimg, int a0) {
  __shared__ __align__(16) uint8_t s_w2[32768];
  __shared__ float s_par[384];
  __shared__ __align__(16) float2 s_bnc[128];

  const int t = threadIdx.x;
  const int wv = t >> 6, l = t & 63, g = l >> 4, q = l & 15;
  const int a = a0 + (blockIdx.x >> 5);
  const int sub = blockIdx.x & 31;

  const uint8_t* w2src = w2img + (size_t)a * 32768;
  #pragma unroll
  for (int i = 0; i < 8; ++i) ((u32v4*)s_w2)[t + 256 * i] = ((const u32v4*)w2src)[t + 256 * i];
  if (t < 128) {
    s_par[PB + t] = b2[a * 128 + t];
    s_par[PG + t] = ln2g[a * 128 + t];
    s_par[PBT + t] = ln2b[a * 128 + t];
    s_bnc[t] = bn1[a * 128 + t];
  }
  __syncthreads();

  float* pS = statS + a * 128;
  float* pQ = statQ + a * 128;

  for (int tt = 0; tt < 4; ++tt) {
    const int tile = sub * 4 + tt;
    uint8_t* ytile = yimg + ((((size_t)(a - a0)) * 128 + tile) << 15);

    f32x4 acc[8][2];
    #pragma unroll
    for (int mf = 0; mf < 8; ++mf) { acc[mf][0] = f4z(); acc[mf][1] = f4z(); }

    #pragma unroll
    for (int ks2 = 0; ks2 < 4; ++ks2) {
      const int k0 = 32 * ks2 + 8 * g;
      f32x4 cf[4];
      #pragma unroll
      for (int i = 0; i < 4; ++i)
        cf[i] = *(const f32x4*)((const uint8_t*)s_bnc + k0 * 8 + 16 * i);
      const int mfp = 2 * ks2 + (g >> 1);
      bf16x8 bfr[2];
      #pragma unroll
      for (int nf = 0; nf < 2; ++nf) {
        const uint8_t* p0 = ytile + ((((uint32_t)mfp << 1) + nf) << 11) +
                            (64 * wv + 32 * (g & 1) + q) * 8;
        u32v2 lo = *(const u32v2*)p0;
        u32v2 hi = *(const u32v2*)(p0 + 128);
        bfr[nf] = bn_frag(lo, hi, cf);
      }
      #pragma unroll
      for (int mf = 0; mf < 8; ++mf) {
        uint32_t r = 16 * mf + q;
        uint32_t cb = ((uint32_t)(64 * ks2 + 16 * g)) ^ ((r & 7u) << 4);
        bf16x8 af = ld_frag(s_w2 + r * 256 + cb);
        acc[mf][0] = mfma16(af, bfr[0], acc[mf][0]);
        acc[mf][1] = mfma16(af, bfr[1], acc[mf][1]);
      }
    }

    bias_ln(acc, s_par, g);
    stats_atomic(acc, pS, pQ, g, q);
    store_ytile(acc, ytile, t);  // overwrite y1 with y2 (per-wave disjoint byte ranges)
  }
}

// ---------- pass 3: h2=BN2+ReLU(y2), logits via MFMA vs padded Wout, softmax, direct store ----
__launch_bounds__(256, 4)
__global__ void pass3_kernel(const int* __restrict__ nidx, const float* __restrict__ boutp,
                             const uint8_t* __restrict__ woimg,
                             const float2* __restrict__ bn2,
                             const uint8_t* __restrict__ yimg,
                             float* __restrict__ out, int a0) {
  __shared__ __align__(16) uint8_t s_wo[4096];
  __shared__ __align__(16) float2 s_bnc[128];
  __shared__ float s_bout[16];

  const int t = threadIdx.x;
  const int wv = t >> 6, l = t & 63, g = l >> 4, q = l & 15;
  const int a = a0 + (blockIdx.x >> 5);
  const int sub = blockIdx.x & 31;

  const int r9 = a / 9, c9 = a - 9 * r9;
  const int deg = 1 + (r9 > 0) + (r9 < 8) + (c9 > 0) + (c9 < 8);
  int nid[5];
  #pragma unroll
  for (int d = 0; d < 5; ++d) nid[d] = __builtin_amdgcn_readfirstlane(nidx[a * 5 + d]);

  ((u32v4*)s_wo)[t] = ((const u32v4*)(woimg + (size_t)a * 4096))[t];
  if (t < 128) s_bnc[t] = bn2[a * 128 + t];
  if (t < 16) s_bout[t] = (t < 5) ? boutp[a * 5 + t] : 0.f;
  __syncthreads();

  // hoist Wout A-frags (tile-invariant)
  bf16x8 afr[4];
  #pragma unroll
  for (int ks2 = 0; ks2 < 4; ++ks2) {
    uint32_t cb = ((uint32_t)(64 * ks2 + 16 * g)) ^ (((uint32_t)q & 7u) << 4);
    afr[ks2] = ld_frag(s_wo + q * 256 + cb);
  }

  for (int tt = 0; tt < 4; ++tt) {
    const int tile = sub * 4 + tt;
    const uint8_t* ytile = yimg + ((((size_t)(a - a0)) * 128 + tile) << 15);

    f32x4 accd[2];
    accd[0] = f4z(); accd[1] = f4z();

    #pragma unroll
    for (int ks2 = 0; ks2 < 4; ++ks2) {
      const int k0 = 32 * ks2 + 8 * g;
      f32x4 cf[4];
      #pragma unroll
      for (int i = 0; i < 4; ++i)
        cf[i] = *(const f32x4*)((const uint8_t*)s_bnc + k0 * 8 + 16 * i);
      const int mfp = 2 * ks2 + (g >> 1);
      #pragma unroll
      for (int nf = 0; nf < 2; ++nf) {
        const uint8_t* p0 = ytile + ((((uint32_t)mfp << 1) + nf) << 11) +
                            (64 * wv + 32 * (g & 1) + q) * 8;
        u32v2 lo = *(const u32v2*)p0;
        u32v2 hi = *(const u32v2*)(p0 + 128);
        accd[nf] = mfma16(afr[ks2], bn_frag(lo, hi, cf), accd[nf]);
      }
    }

    // + bout, collect d4 from the g^1 row-group, softmax over valid d
    #pragma unroll
    for (int nf = 0; nf < 2; ++nf) {
      #pragma unroll
      for (int rg = 0; rg < 4; ++rg) accd[nf][rg] += s_bout[4 * g + rg];
    }
    float d4[2];
    d4[0] = __shfl_xor(accd[0][0], 16);
    d4[1] = __shfl_xor(accd[1][0], 16);

    float p[2][5];
    #pragma unroll
    for (int nf = 0; nf < 2; ++nf) {
      float v[5] = {accd[nf][0], accd[nf][1], accd[nf][2], accd[nf][3], d4[nf]};
      float mx = v[0];
      #pragma unroll
      for (int d = 1; d < 5; ++d)
        if (d < deg) mx = fmaxf(mx, v[d]);
      float den = 0.f;
      #pragma unroll
      for (int d = 0; d < 5; ++d) {
        float e = (d < deg) ? __expf(v[d] - mx) : 0.f;
        p[nf][d] = e;
        den += e;
      }
      float inv = 1.f / den;
      #pragma unroll
      for (int d = 0; d < 5; ++d) p[nf][d] *= inv;
    }

    // hand nf=1 row to g==2 lanes; g==0 stores nf=0 row, g==2 stores nf=1 row
    float p5[5];
    #pragma unroll
    for (int d = 0; d < 5; ++d) {
      float pr = __shfl_xor(p[1][d], 32);
      p5[d] = (g == 0) ? p[0][d] : pr;
    }

    if (g == 0 || g == 2) {
      const int brow = tile * 128 + 32 * wv + ((g == 2) ? 16 : 0) + q;
      float* orow = out + ((size_t)brow * 81 + (size_t)a) * 81;
      #pragma unroll
      for (int c = 0; c < 20; ++c) {
        f32x4u v = {0.f, 0.f, 0.f, 0.f};
        #pragma unroll
        for (int d = 0; d < 5; ++d)
          if (d < deg && (nid[d] >> 2) == c) v[nid[d] & 3] = p5[d];
        *(f32x4u*)(orow + 4 * c) = v;
      }
      float vl = 0.f;
      #pragma unroll
      for (int d = 0; d < 5; ++d)
        if (d < deg && nid[d] == 80) vl = p5[d];
      orow[80] = vl;
    }
  }
}

extern "C" void kernel_launch(void* const* d_in, const int* in_sizes, int n_in,
                              void* d_out, int out_size, void* d_ws, size_t ws_size,
                              hipStream_t stream) {
  (void)in_sizes; (void)n_in; (void)out_size;
  const float* obs = (const float*)d_in[0];
  const int* nidx = (const int*)d_in[1];
  // d_in[2] = neigh_mask (derived structurally)
  const float* W1 = (const float*)d_in[3];
  const float* b1 = (const float*)d_in[4];
  const float* ln1g = (const float*)d_in[5];
  const float* ln1b = (const float*)d_in[6];
  const float* bnb1 = (const float*)d_in[7];
  const float* W2 = (const float*)d_in[8];
  const float* b2 = (const float*)d_in[9];
  const float* ln2g = (const float*)d_in[10];
  const float* ln2b = (const float*)d_in[11];
  const float* bnb2 = (const float*)d_in[12];
  const float* Wout = (const float*)d_in[13];
  const float* bout = (const float*)d_in[14];
  float* out = (float*)d_out;
  uint8_t* ws = (uint8_t*)d_ws;

  uint8_t* w1img   = ws;                       // 1,327,104
  uint8_t* w2img   = ws + 1327104;             // 2,654,208
  uint8_t* woimg   = ws + 3981312;             //   331,776
  uint8_t* globimg = ws + 4313088;             // 1,572,864
  float* statS1 = (float*)(ws + 5885952);      //    41,472 each
  float* statQ1 = (float*)(ws + 5927424);
  float* statS2 = (float*)(ws + 5968896);
  float* statQ2 = (float*)(ws + 6010368);
  float2* bn1 = (float2*)(ws + 6051840);       //    82,944 each
  float2* bn2 = (float2*)(ws + 6134784);
  uint8_t* yimg = ws + 6217728;                // na * 4 MB

  size_t ybytes = (ws_size > 6217728) ? ws_size - 6217728 : 0;
  int na = (int)(ybytes / 4194304);
  if (na < 1) na = 1;
  if (na > N_AG) na = N_AG;

  prep_weights<<<N_AG, 256, 0, stream>>>(W1, W2, Wout, w1img, w2img, woimg);
  prep_obs<<<64, 256, 0, stream>>>(obs, globimg);
  hipMemsetAsync(statS1, 0, 4 * 41472, stream);

  for (int a0 = 0; a0 < N_AG; a0 += na) {
    int nc = N_AG - a0;
    if (nc > na) nc = na;
    pass1_kernel<<<nc * 32, 256, 0, stream>>>(obs, nidx, b1, ln1g, ln1b, w1img, globimg,
                                              statS1, statQ1, yimg, a0);
    reduce_bn<<<nc, 128, 0, stream>>>(statS1, statQ1, bnb1, bn1, a0);
    pass2_kernel<<<nc * 32, 256, 0, stream>>>(b2, ln2g, ln2b, w2img, bn1,
                                              statS2, statQ2, yimg, a0);
    reduce_bn<<<nc, 128, 0, stream>>>(statS2, statQ2, bnb2, bn2, a0);
    pass3_kernel<<<nc * 32, 256, 0, stream>>>(nidx, bout, woimg, bn2, yimg, out, a0);
  }
}